// Round 7
// baseline (1471.248 us; speedup 1.0000x reference)
//
#include <hip/hip_runtime.h>
#include <cstddef>

// ---------- types ----------
typedef _Float16 f16x8 __attribute__((ext_vector_type(8)));
typedef short    s16x8 __attribute__((ext_vector_type(8)));
typedef short    s16x4 __attribute__((ext_vector_type(4)));
typedef float    f32x4 __attribute__((ext_vector_type(4)));

#define MFMA_F16(a, b, c) __builtin_amdgcn_mfma_f32_16x16x32_f16((a), (b), (c), 0, 0, 0)

#if __has_builtin(__builtin_amdgcn_sched_barrier)
#define SCHED_FENCE() __builtin_amdgcn_sched_barrier(0)
#else
#define SCHED_FENCE() do {} while (0)
#endif

#if __has_builtin(__builtin_amdgcn_rcpf)
__device__ __forceinline__ float fast_rcp(float x) { return __builtin_amdgcn_rcpf(x); }
#else
__device__ __forceinline__ float fast_rcp(float x) { return 1.f / x; }
#endif

__device__ __forceinline__ f16x8 ld8(const short* p) {
  return __builtin_bit_cast(f16x8, *(const s16x8*)p);
}
__device__ __forceinline__ float s2f(short s) {
  return (float)__builtin_bit_cast(_Float16, s);
}

// ---------- fp32 -> fp16 casts, one launch ----------
struct CastDesc { const float* src; short* dst; int n; };
struct CastArgs { CastDesc d[7]; };

__global__ void cast_many(CastArgs a) {
  const int tid = blockIdx.x * blockDim.x + threadIdx.x;
  const int stride = gridDim.x * blockDim.x;
#pragma unroll
  for (int j = 0; j < 7; j++) {
    const float* __restrict__ s = a.d[j].src;
    short* __restrict__ o = a.d[j].dst;
    const int n = a.d[j].n;
    for (int i = tid; i < n; i += stride)
      o[i] = __builtin_bit_cast(short, (_Float16)s[i]);
  }
}

// ---------- xg projection GEMM ----------
// Computes xgT[wg][t][NC][16] (fp16) = per-16-batch-row tile of x_t @ Wih^T,
// laid out so the rec kernel's epilogue reads are fully coalesced 8B vectors.
// grid = (T, B/16); block = 4 waves; wave handles col-tiles wid, wid+4, ...
template <int K, int NC, bool AF32>
__global__ __launch_bounds__(256)
void xg_gemm(const void* __restrict__ Araw, const short* __restrict__ W,
             short* __restrict__ xgT) {
  constexpr int T = 256;
  constexpr int KF = K / 32;
  const int lane = threadIdx.x & 63, wid = threadIdx.x >> 6;
  const int p = lane & 15, q = lane >> 4;
  const int t = blockIdx.x, wg = blockIdx.y;
  const int b0 = wg * 16;

  f16x8 ax[KF];
  if constexpr (AF32) {
    const float* A = (const float*)Araw;
    const float* ap = A + ((size_t)(b0 + p) * T + t) * K + q * 8;
#pragma unroll
    for (int k = 0; k < KF; k++) {
      f32x4 a0 = *(const f32x4*)(ap + k * 32);
      f32x4 a1 = *(const f32x4*)(ap + k * 32 + 4);
      f16x8 v;
#pragma unroll
      for (int i = 0; i < 4; i++) { v[i] = (_Float16)a0[i]; v[4 + i] = (_Float16)a1[i]; }
      ax[k] = v;
    }
  } else {
    const short* A = (const short*)Araw;
    const short* ap = A + ((size_t)(b0 + p) * T + t) * K + q * 8;
#pragma unroll
    for (int k = 0; k < KF; k++) ax[k] = ld8(ap + k * 32);
  }

  short* outb = xgT + ((size_t)wg * T + t) * NC * 16;
#pragma unroll 1
  for (int c = wid; c < NC / 16; c += 4) {
    const short* wp = W + (size_t)(c * 16 + p) * K + q * 8;
    f32x4 acc = {0.f, 0.f, 0.f, 0.f};
#pragma unroll
    for (int k = 0; k < KF; k++) acc = MFMA_F16(ax[k], ld8(wp + k * 32), acc);
    s16x4 o;
#pragma unroll
    for (int r = 0; r < 4; r++) o[r] = __builtin_bit_cast(short, (_Float16)acc[r]);
    *(s16x4*)&outb[(size_t)(c * 16 + p) * 16 + q * 4] = o;
  }
}

// ---------- GRU recurrence ----------
// One wg = 16 batch rows, NW waves; wave owns JT 16-col j-tiles.
// WLDS==3: whole whh LDS-resident -> zero per-step weight traffic.
// WLDS==1 (H=256): whh_n LDS-resident; whh_r/z streamed EVERY step with
//   issue-early (all loads first, sched_barrier, n-rec LDS work in between,
//   consume after) -> latency overlapped, no register residency assumed.
// XG: input projection precomputed (xgT); epilogue adds it via coalesced
//   8B reads prefetched one step ahead. !XG: x + wih streamed per step.
template <int H, int NW, int JT, int WLDS, bool XG, int HIN, bool STORE_SEQ>
__global__ __launch_bounds__(NW * 64)
__attribute__((amdgpu_waves_per_eu(NW / 4 > 0 ? NW / 4 : 1, NW / 4 > 0 ? NW / 4 : 1)))
void gru_rec(const short* __restrict__ xin,   // [B,T,HIN] fp16 (!XG)
             const short* __restrict__ xgT,   // tiled xg (XG)
             const short* __restrict__ Wih,   // [3H,HIN] fp16 (!XG)
             const short* __restrict__ Whh,   // [3H,H] fp16
             const float* __restrict__ b_ih,
             const float* __restrict__ b_hh,
             short* __restrict__ hseq,        // [B,T,H] fp16 if STORE_SEQ
             float* __restrict__ hlast) {     // [B,H] fp32 if !STORE_SEQ
  static_assert(NW * 16 * JT == H, "tiling must cover H");
  constexpr int T   = 256;
  constexpr int KS  = H / 32;
  constexpr int KSI = HIN / 32;
  constexpr int HP  = H + 8;
  constexpr int WROWS = WLDS * H;
  constexpr int NSTREAM = (WLDS == 1) ? KS : 0;  // streamed r/z k-frags

  extern __shared__ __align__(16) short smem[];
  short* whhL = smem;                // [WROWS][HP]
  short* hb   = smem + WROWS * HP;   // [2][16][HP]

  const int tid  = threadIdx.x;
  const int lane = tid & 63;
  const int wid  = tid >> 6;
  const int p = lane & 15;
  const int q = lane >> 4;
  const int wg = blockIdx.x;
  const int b0 = wg * 16;
  const int j0 = wid * (16 * JT);

  for (int i = tid; i < 2 * 16 * HP; i += NW * 64) hb[i] = 0;

  // stage LDS-resident whh rows (L1: n-gate only; else all gates)
  constexpr int GOFF = (WLDS == 1) ? 2 * H : 0;
  constexpr int KV = H / 8;
  for (int i = tid; i < WROWS * KV; i += NW * 64) {
    const int row = i / KV, kc = i - row * KV;
    *(s16x8*)&whhL[row * HP + kc * 8] =
        *(const s16x8*)&Whh[(size_t)(GOFF + row) * H + kc * 8];
  }

  // t-invariant biases + pointers
  float brz_r[JT], brz_z[JT], bxn[JT], bhn[JT];
  int wrow[JT];
  const short* whh_rz[2][JT];        // WLDS==1: streamed r/z row bases
  const short* wih_p[3][JT];         // !XG: wih row bases
  const short* xgp[3][JT];           // XG: xg element bases (per t: +3H*16)
  constexpr size_t XGSTRIDE = (size_t)3 * H * 16;
#pragma unroll
  for (int jt = 0; jt < JT; jt++) {
    const int col = j0 + jt * 16 + p;
    brz_r[jt] = b_ih[col] + b_hh[col];
    brz_z[jt] = b_ih[H + col] + b_hh[H + col];
    bxn[jt]   = b_ih[2 * H + col];
    bhn[jt]   = b_hh[2 * H + col];
    wrow[jt]  = col;
    if constexpr (WLDS == 1) {
      whh_rz[0][jt] = Whh + (size_t)(0 * H + col) * H + q * 8;
      whh_rz[1][jt] = Whh + (size_t)(1 * H + col) * H + q * 8;
    }
    if constexpr (!XG) {
#pragma unroll
      for (int g = 0; g < 3; g++)
        wih_p[g][jt] = Wih + (size_t)(g * H + col) * HIN + q * 8;
    } else {
#pragma unroll
      for (int g = 0; g < 3; g++)
        xgp[g][jt] = xgT + ((size_t)wg * T * 3 * H + (size_t)(g * H + col)) * 16 + q * 4;
    }
  }

  float hprev[JT][4];
#pragma unroll
  for (int jt = 0; jt < JT; jt++)
#pragma unroll
    for (int r = 0; r < 4; r++) hprev[jt][r] = 0.f;

  const short* xp = XG ? nullptr : (xin + (size_t)(b0 + p) * T * HIN + q * 8);

  // prime xg prefetch (t = 0)
  s16x4 xgc[3][JT];
  if constexpr (XG) {
#pragma unroll
    for (int g = 0; g < 3; g++)
#pragma unroll
      for (int jt = 0; jt < JT; jt++) xgc[g][jt] = *(const s16x4*)xgp[g][jt];
  }

  __syncthreads();

  for (int t = 0; t < T; t++) {
    const int cur = t & 1;
    short* hbc = hb + cur * 16 * HP;
    short* hbn = hb + (cur ^ 1) * 16 * HP;

    // ---- early-issue global loads (consumed after n-rec) ----
    f16x8 wst[2][JT][NSTREAM > 0 ? NSTREAM : 1];  // streamed whh r/z
    if constexpr (WLDS == 1) {
#pragma unroll
      for (int g = 0; g < 2; g++)
#pragma unroll
        for (int jt = 0; jt < JT; jt++)
#pragma unroll
          for (int k = 0; k < KS; k++)
            wst[g][jt][k] = ld8(whh_rz[g][jt] + k * 32);
    }
    f16x8 axc[XG ? 1 : KSI];
    f16x8 wis[XG ? 1 : 3][XG ? 1 : JT][XG ? 1 : KSI];
    if constexpr (!XG) {
#pragma unroll
      for (int k = 0; k < KSI; k++) axc[k] = ld8(xp + k * 32);
#pragma unroll
      for (int g = 0; g < 3; g++)
#pragma unroll
        for (int jt = 0; jt < JT; jt++)
#pragma unroll
          for (int k = 0; k < KSI; k++) wis[g][jt][k] = ld8(wih_p[g][jt] + k * 32);
    }
    s16x4 xgn[3][XG ? JT : 1];
    if constexpr (XG) {
      const size_t toff = (size_t)(t + 1) * XGSTRIDE;  // last step reads pad row
#pragma unroll
      for (int g = 0; g < 3; g++)
#pragma unroll
        for (int jt = 0; jt < JT; jt++)
          xgn[g][jt] = *(const s16x4*)(xgp[g][jt] + toff);
    }
    SCHED_FENCE();  // keep the issue block above the LDS work

    // ---- h fragments + LDS-resident recurrence ----
    f32x4 ar[JT], az[JT], an[JT], xa[JT];
#pragma unroll
    for (int jt = 0; jt < JT; jt++) {
      ar[jt] = f32x4{0.f, 0.f, 0.f, 0.f};
      az[jt] = f32x4{0.f, 0.f, 0.f, 0.f};
      an[jt] = f32x4{0.f, 0.f, 0.f, 0.f};
      xa[jt] = f32x4{0.f, 0.f, 0.f, 0.f};
    }
    f16x8 ah[KS];
#pragma unroll
    for (int k = 0; k < KS; k++) ah[k] = ld8(&hbc[p * HP + k * 32 + q * 8]);

#pragma unroll
    for (int k = 0; k < KS; k++) {
#pragma unroll
      for (int jt = 0; jt < JT; jt++) {
        if constexpr (WLDS == 1) {
          const f16x8 wnk = ld8(&whhL[wrow[jt] * HP + k * 32 + q * 8]);
          an[jt] = MFMA_F16(ah[k], wnk, an[jt]);
        } else {
          const f16x8 wrk = ld8(&whhL[(0 * H + wrow[jt]) * HP + k * 32 + q * 8]);
          const f16x8 wzk = ld8(&whhL[(1 * H + wrow[jt]) * HP + k * 32 + q * 8]);
          const f16x8 wnk = ld8(&whhL[(2 * H + wrow[jt]) * HP + k * 32 + q * 8]);
          ar[jt] = MFMA_F16(ah[k], wrk, ar[jt]);
          az[jt] = MFMA_F16(ah[k], wzk, az[jt]);
          an[jt] = MFMA_F16(ah[k], wnk, an[jt]);
        }
      }
    }

    // ---- consume streamed loads ----
    if constexpr (WLDS == 1) {
#pragma unroll
      for (int k = 0; k < KS; k++)
#pragma unroll
        for (int jt = 0; jt < JT; jt++) {
          ar[jt] = MFMA_F16(ah[k], wst[0][jt][k], ar[jt]);
          az[jt] = MFMA_F16(ah[k], wst[1][jt][k], az[jt]);
        }
    }
    if constexpr (!XG) {
#pragma unroll
      for (int k = 0; k < KSI; k++)
#pragma unroll
        for (int jt = 0; jt < JT; jt++) {
          ar[jt] = MFMA_F16(axc[k], wis[0][jt][k], ar[jt]);
          az[jt] = MFMA_F16(axc[k], wis[1][jt][k], az[jt]);
          xa[jt] = MFMA_F16(axc[k], wis[2][jt][k], xa[jt]);
        }
    }

    // ---- epilogue: C/D layout col = lane&15, row = q*4+r ----
#pragma unroll
    for (int jt = 0; jt < JT; jt++) {
#pragma unroll
      for (int r = 0; r < 4; r++) {
        const int bm = q * 4 + r;
        const int col = j0 + jt * 16 + p;
        float xr, xz, xn;
        if constexpr (XG) {
          xr = s2f(xgc[0][jt][r]);
          xz = s2f(xgc[1][jt][r]);
          xn = s2f(xgc[2][jt][r]);
        } else {
          xr = 0.f; xz = 0.f; xn = xa[jt][r];
        }
        const float rpre = ar[jt][r] + xr + brz_r[jt];
        const float zpre = az[jt][r] + xz + brz_z[jt];
        const float ghn  = an[jt][r] + bhn[jt];
        const float rg = fast_rcp(1.f + __expf(-rpre));
        const float zg = fast_rcp(1.f + __expf(-zpre));
        const float narg = xn + bxn[jt] + rg * ghn;
        const float e2 = __expf(2.f * narg);
        const float ng = 1.f - 2.f * fast_rcp(e2 + 1.f);  // tanh
        const float hnew = (1.f - zg) * ng + zg * hprev[jt][r];
        hprev[jt][r] = hnew;
        const _Float16 hf = (_Float16)hnew;
        hbn[bm * HP + col] = __builtin_bit_cast(short, hf);
        if (STORE_SEQ) {
          hseq[((size_t)(b0 + bm) * T + t) * H + col] = __builtin_bit_cast(short, hf);
        } else if (t == T - 1) {
          hlast[(size_t)(b0 + bm) * H + col] = hnew;
        }
      }
    }
    if constexpr (XG) {
#pragma unroll
      for (int g = 0; g < 3; g++)
#pragma unroll
        for (int jt = 0; jt < JT; jt++) xgc[g][jt] = xgn[g][jt];
    } else {
      xp += HIN;
    }
    __syncthreads();
  }
}

// ---------- dense head ----------
__global__ void dense_kernel(const float* __restrict__ hl, const float* __restrict__ Wd,
                             const float* __restrict__ bd, float* __restrict__ out) {
  const int b = blockIdx.x * 64 + threadIdx.x;
  float a = bd[0];
#pragma unroll
  for (int k = 0; k < 64; k++) a = fmaf(hl[b * 64 + k], Wd[k], a);
  out[b] = a;
}

// ---------- host ----------
extern "C" void kernel_launch(void* const* d_in, const int* in_sizes, int n_in,
                              void* d_out, int out_size, void* d_ws, size_t ws_size,
                              hipStream_t stream) {
  constexpr int B = 512, T = 256, F = 64;
  constexpr int H1 = 256, H2 = 128, H3 = 64;
  constexpr int M = B * T;

  const float* x     = (const float*)d_in[0];
  const float* W_ih1 = (const float*)d_in[1];
  const float* W_hh1 = (const float*)d_in[2];
  const float* b_ih1 = (const float*)d_in[3];
  const float* b_hh1 = (const float*)d_in[4];
  const float* W_ih2 = (const float*)d_in[5];
  const float* W_hh2 = (const float*)d_in[6];
  const float* b_ih2 = (const float*)d_in[7];
  const float* b_hh2 = (const float*)d_in[8];
  const float* W_ih3 = (const float*)d_in[9];
  const float* W_hh3 = (const float*)d_in[10];
  const float* b_ih3 = (const float*)d_in[11];
  const float* b_hh3 = (const float*)d_in[12];
  const float* W_d   = (const float*)d_in[13];
  const float* b_d   = (const float*)d_in[14];
  float* out = (float*)d_out;

  char* ws = (char*)d_ws;
  size_t off = 0;
  auto alloc = [&](size_t bytes) -> char* {
    char* pp = ws + off;
    off = (off + bytes + 255) & ~(size_t)255;
    return pp;
  };

  const int nx    = M * F;
  const int nwih1 = 3 * H1 * F,  nwhh1 = 3 * H1 * H1;
  const int nwih2 = 3 * H2 * H1, nwhh2 = 3 * H2 * H2;
  const int nwih3 = 3 * H3 * H2, nwhh3 = 3 * H3 * H3;

  short* xh    = (short*)alloc((size_t)nx * 2);
  short* wih1  = (short*)alloc((size_t)nwih1 * 2);
  short* whh1  = (short*)alloc((size_t)nwhh1 * 2);
  short* wih2  = (short*)alloc((size_t)nwih2 * 2);
  short* whh2  = (short*)alloc((size_t)nwhh2 * 2);
  short* wih3  = (short*)alloc((size_t)nwih3 * 2);
  short* whh3  = (short*)alloc((size_t)nwhh3 * 2);
  short* h1    = (short*)alloc((size_t)M * H1 * 2);
  short* h2    = (short*)alloc((size_t)M * H2 * 2);
  float* hlast = (float*)alloc((size_t)B * H3 * 4);
  // xg tile buffer (largest: L1 = (wg*T+1 rows) * 3H1 * 16 fp16), reused by all
  const size_t xg_elems = ((size_t)(B / 16) * T + 1) * (3 * H1) * 16;
  short* xgT = (short*)alloc(xg_elems * 2);
  const bool tierA = (off <= ws_size);  // ~322 MiB needed; else no-xg fallback
  (void)n_in; (void)in_sizes; (void)out_size;

  CastArgs ca;
  ca.d[0] = {x, xh, nx};
  ca.d[1] = {W_ih1, wih1, nwih1};
  ca.d[2] = {W_hh1, whh1, nwhh1};
  ca.d[3] = {W_ih2, wih2, nwih2};
  ca.d[4] = {W_hh2, whh2, nwhh2};
  ca.d[5] = {W_ih3, wih3, nwih3};
  ca.d[6] = {W_hh3, whh3, nwhh3};
  cast_many<<<1024, 256, 0, stream>>>(ca);

  constexpr int SM1 = (1 * H1 + 32) * (H1 + 8) * 2;  // 152064
  constexpr int SM2 = (3 * H2 + 32) * (H2 + 8) * 2;  // 113152
  constexpr int SM3 = (3 * H3 + 32) * (H3 + 8) * 2;  //  32256

  if (tierA) {
    auto* r1 = gru_rec<H1, 8, 2, 1, true, F,  true>;
    auto* r2 = gru_rec<H2, 8, 1, 3, true, H1, true>;
    auto* r3 = gru_rec<H3, 4, 1, 3, true, H2, false>;
    (void)hipFuncSetAttribute((const void*)r1, hipFuncAttributeMaxDynamicSharedMemorySize, SM1);
    (void)hipFuncSetAttribute((const void*)r2, hipFuncAttributeMaxDynamicSharedMemorySize, SM2);
    (void)hipFuncSetAttribute((const void*)r3, hipFuncAttributeMaxDynamicSharedMemorySize, SM3);

    xg_gemm<F, 3 * H1, true><<<dim3(T, B / 16), 256, 0, stream>>>(x, wih1, xgT);
    r1<<<B / 16, 8 * 64, SM1, stream>>>(nullptr, xgT, nullptr, whh1, b_ih1, b_hh1, h1, nullptr);
    xg_gemm<H1, 3 * H2, false><<<dim3(T, B / 16), 256, 0, stream>>>(h1, wih2, xgT);
    r2<<<B / 16, 8 * 64, SM2, stream>>>(nullptr, xgT, nullptr, whh2, b_ih2, b_hh2, h2, nullptr);
    xg_gemm<H2, 3 * H3, false><<<dim3(T, B / 16), 256, 0, stream>>>(h2, wih3, xgT);
    r3<<<B / 16, 4 * 64, SM3, stream>>>(nullptr, xgT, nullptr, whh3, b_ih3, b_hh3, nullptr, hlast);
  } else {
    auto* r1 = gru_rec<H1, 8, 2, 1, false, F,  true>;
    auto* r2 = gru_rec<H2, 8, 1, 3, false, H1, true>;
    auto* r3 = gru_rec<H3, 4, 1, 3, false, H2, false>;
    (void)hipFuncSetAttribute((const void*)r1, hipFuncAttributeMaxDynamicSharedMemorySize, SM1);
    (void)hipFuncSetAttribute((const void*)r2, hipFuncAttributeMaxDynamicSharedMemorySize, SM2);
    (void)hipFuncSetAttribute((const void*)r3, hipFuncAttributeMaxDynamicSharedMemorySize, SM3);

    r1<<<B / 16, 8 * 64, SM1, stream>>>(xh, nullptr, wih1, whh1, b_ih1, b_hh1, h1, nullptr);
    r2<<<B / 16, 8 * 64, SM2, stream>>>(h1, nullptr, wih2, whh2, b_ih2, b_hh2, h2, nullptr);
    r3<<<B / 16, 4 * 64, SM3, stream>>>(h2, nullptr, wih3, whh3, b_ih3, b_hh3, nullptr, hlast);
  }

  dense_kernel<<<B / 64, 64, 0, stream>>>(hlast, W_d, b_d, out);
}